// Round 6
// baseline (838.537 us; speedup 1.0000x reference)
//
#include <hip/hip_runtime.h>
#include <math.h>

#define EPS 1e-12f
#define NN 32
#define CDIM 512
#define SDIM 3600
#define KDIM 64

// ---------------------------------------------------------------------------
// K0: transpose W[64][512] -> wT[512][64]
// ---------------------------------------------------------------------------
__global__ __launch_bounds__(256) void k0_transpose(
    const float* __restrict__ w, float* __restrict__ wT)
{
  int i = blockIdx.x * 256 + threadIdx.x;   // 32768 total
  int k = i >> 9;        // /512
  int c = i & 511;
  wT[c * KDIM + k] = w[i];
}

// ---------------------------------------------------------------------------
// K1: per-pixel (2 px/thread): nrm = sum_c x^2 ; acc[k] = sum_c w[k,c]*x[c]
//     softmax over k of acc*invn ; write a[n,k,s], invn[n,s]
// ---------------------------------------------------------------------------
__device__ __forceinline__ void k1_finish(
    float* acc, float nrm, int n, int s, bool valid,
    float* __restrict__ a, float* __restrict__ invn_out)
{
  float invn = 1.f / fmaxf(sqrtf(nrm), EPS);
  float m = acc[0];
  #pragma unroll
  for (int k = 1; k < 64; ++k) m = fmaxf(m, acc[k]);
  float sum = 0.f;
  #pragma unroll
  for (int k = 0; k < 64; ++k) {
    float e = __expf((acc[k] - m) * invn);
    acc[k] = e;
    sum += e;
  }
  float rs = 1.f / sum;
  if (valid) {
    float* ap = a + (size_t)n * KDIM * SDIM + s;
    #pragma unroll
    for (int k = 0; k < 64; ++k) ap[(size_t)k * SDIM] = acc[k] * rs;
    invn_out[n * SDIM + s] = invn;
  }
}

__global__ __launch_bounds__(128) void k1_softmax(
    const float* __restrict__ x, const float* __restrict__ wT,
    float* __restrict__ a, float* __restrict__ invn_out)
{
  __shared__ float wt[64 * 64];             // wt[cc][k] tile (16 KB)
  const int n = blockIdx.y;
  const int s0r = blockIdx.x * 256 + threadIdx.x;
  const int s1r = s0r + 128;
  const bool v0 = s0r < SDIM, v1 = s1r < SDIM;
  const int s0 = v0 ? s0r : (SDIM - 1);
  const int s1 = v1 ? s1r : (SDIM - 1);
  const float* xb = x + (size_t)n * CDIM * SDIM;
  const float* xp0 = xb + s0;
  const float* xp1 = xb + s1;

  float acc0[64], acc1[64];
  #pragma unroll
  for (int k = 0; k < 64; ++k) { acc0[k] = 0.f; acc1[k] = 0.f; }
  float nrm0 = 0.f, nrm1 = 0.f;

  for (int c0 = 0; c0 < CDIM; c0 += 64) {
    __syncthreads();
    // stage wT[c0..c0+63][0..63] -> wt, plain contiguous float4 copy
    const float4* src = (const float4*)(wT + c0 * 64);
    float4* dst = (float4*)wt;
    for (int i = threadIdx.x; i < 1024; i += 128) dst[i] = src[i];
    __syncthreads();

    for (int cc = 0; cc < 64; ++cc) {
      float xv0 = xp0[(size_t)(c0 + cc) * SDIM];
      float xv1 = xp1[(size_t)(c0 + cc) * SDIM];
      nrm0 = fmaf(xv0, xv0, nrm0);
      nrm1 = fmaf(xv1, xv1, nrm1);
      const float4* wr = (const float4*)(&wt[cc * 64]);
      #pragma unroll
      for (int q = 0; q < 16; ++q) {
        float4 w4 = wr[q];
        acc0[q * 4 + 0] = fmaf(w4.x, xv0, acc0[q * 4 + 0]);
        acc0[q * 4 + 1] = fmaf(w4.y, xv0, acc0[q * 4 + 1]);
        acc0[q * 4 + 2] = fmaf(w4.z, xv0, acc0[q * 4 + 2]);
        acc0[q * 4 + 3] = fmaf(w4.w, xv0, acc0[q * 4 + 3]);
        acc1[q * 4 + 0] = fmaf(w4.x, xv1, acc1[q * 4 + 0]);
        acc1[q * 4 + 1] = fmaf(w4.y, xv1, acc1[q * 4 + 1]);
        acc1[q * 4 + 2] = fmaf(w4.z, xv1, acc1[q * 4 + 2]);
        acc1[q * 4 + 3] = fmaf(w4.w, xv1, acc1[q * 4 + 3]);
      }
    }
  }

  k1_finish(acc0, nrm0, n, s0, v0, a, invn_out);
  k1_finish(acc1, nrm1, n, s1, v1, a, invn_out);
}

// ---------------------------------------------------------------------------
// K2: aggp[sp][n][k][c] = sum_{s in split} a[n,k,s] * x[n,c,s]*invn[n,s]
// block: 64k x 128c tile, 256 threads (each 4k x (4+4)c), s-chunked staging
// lane c-columns split as {tc*4, tc*4+64} so LDS reads are 2-way (free)
// ---------------------------------------------------------------------------
__global__ __launch_bounds__(256) void k2_agg(
    const float* __restrict__ a, const float* __restrict__ x,
    const float* __restrict__ invn, float* __restrict__ aggp)
{
  __shared__ float xs[60 * 132];   // xs[s][c], stride 132 (528B, 16B-aligned)
  __shared__ float at[60 * 72];    // at[s][k], stride 72
  const int n = blockIdx.y;
  const int c0 = blockIdx.x * 128;
  const int sbase = blockIdx.z * 900;
  const int tk = threadIdx.x >> 4;   // 0..15 -> k = tk*4..tk*4+3
  const int tc = threadIdx.x & 15;   // 0..15 -> c = c0+tc*4 and c0+64+tc*4

  float acc[32];
  #pragma unroll
  for (int i = 0; i < 32; ++i) acc[i] = 0.f;

  for (int ch = 0; ch < 15; ++ch) {
    const int ss = sbase + ch * 60;
    __syncthreads();
    for (int i = threadIdx.x; i < 7680; i += 256) {     // 128c x 60s
      int c = i / 60;
      int s = i - c * 60;
      xs[s * 132 + c] = x[((size_t)n * CDIM + c0 + c) * SDIM + ss + s] *
                        invn[n * SDIM + ss + s];
    }
    for (int i = threadIdx.x; i < 3840; i += 256) {     // 64k x 60s
      int k = i / 60;
      int s = i - k * 60;
      at[s * 72 + k] = a[((size_t)n * KDIM + k) * SDIM + ss + s];
    }
    __syncthreads();
    #pragma unroll 4
    for (int s = 0; s < 60; ++s) {
      float4 av  = *(const float4*)(&at[s * 72 + tk * 4]);
      float4 xv0 = *(const float4*)(&xs[s * 132 + tc * 4]);
      float4 xv1 = *(const float4*)(&xs[s * 132 + 64 + tc * 4]);
      #pragma unroll
      for (int j = 0; j < 4; ++j) {
        float aj = (j == 0) ? av.x : (j == 1) ? av.y : (j == 2) ? av.z : av.w;
        acc[j * 8 + 0] = fmaf(aj, xv0.x, acc[j * 8 + 0]);
        acc[j * 8 + 1] = fmaf(aj, xv0.y, acc[j * 8 + 1]);
        acc[j * 8 + 2] = fmaf(aj, xv0.z, acc[j * 8 + 2]);
        acc[j * 8 + 3] = fmaf(aj, xv0.w, acc[j * 8 + 3]);
        acc[j * 8 + 4] = fmaf(aj, xv1.x, acc[j * 8 + 4]);
        acc[j * 8 + 5] = fmaf(aj, xv1.y, acc[j * 8 + 5]);
        acc[j * 8 + 6] = fmaf(aj, xv1.z, acc[j * 8 + 6]);
        acc[j * 8 + 7] = fmaf(aj, xv1.w, acc[j * 8 + 7]);
      }
    }
  }

  float* outp = aggp + ((size_t)blockIdx.z * NN + n) * KDIM * CDIM;
  #pragma unroll
  for (int j = 0; j < 4; ++j) {
    int k = tk * 4 + j;
    *(float4*)(&outp[(size_t)k * CDIM + c0 + tc * 4]) =
        make_float4(acc[j*8+0], acc[j*8+1], acc[j*8+2], acc[j*8+3]);
    *(float4*)(&outp[(size_t)k * CDIM + c0 + 64 + tc * 4]) =
        make_float4(acc[j*8+4], acc[j*8+5], acc[j*8+6], acc[j*8+7]);
  }
}

// ---------------------------------------------------------------------------
// K3: per (n,k): asum = sum_s a ; row = sum_sp aggp - asum*centroid ;
//     intra-normalize ; write out ; atomicAdd per-n sumsq
// ---------------------------------------------------------------------------
__global__ __launch_bounds__(256) void k3_finalize(
    const float* __restrict__ a, const float* __restrict__ aggp,
    const float* __restrict__ cent, float* __restrict__ out,
    float* __restrict__ gsum)
{
  const int k = blockIdx.x;
  const int n = blockIdx.y;
  __shared__ float red[16];

  float p = 0.f;
  const float* ap = a + ((size_t)n * KDIM + k) * SDIM;
  for (int s = threadIdx.x; s < SDIM; s += 256) p += ap[s];
  #pragma unroll
  for (int o = 32; o > 0; o >>= 1) p += __shfl_xor(p, o);
  int wid = threadIdx.x >> 6;
  if ((threadIdx.x & 63) == 0) red[wid] = p;
  __syncthreads();
  float asum = red[0] + red[1] + red[2] + red[3];

  float v[2];
  float ss_ = 0.f;
  #pragma unroll
  for (int r = 0; r < 2; ++r) {
    int c = r * 256 + threadIdx.x;
    float t = 0.f;
    #pragma unroll
    for (int sp = 0; sp < 4; ++sp)
      t += aggp[(((size_t)sp * NN + n) * KDIM + k) * CDIM + c];
    t -= asum * cent[k * CDIM + c];
    v[r] = t;
    ss_ = fmaf(t, t, ss_);
  }
  #pragma unroll
  for (int o = 32; o > 0; o >>= 1) ss_ += __shfl_xor(ss_, o);
  if ((threadIdx.x & 63) == 0) red[8 + wid] = ss_;
  __syncthreads();
  float rowss = red[8] + red[9] + red[10] + red[11];

  float scale = 1.f / fmaxf(sqrtf(rowss), EPS);
  #pragma unroll
  for (int r = 0; r < 2; ++r)
    out[((size_t)n * KDIM + k) * CDIM + r * 256 + threadIdx.x] = v[r] * scale;
  if (threadIdx.x == 0) atomicAdd(&gsum[n], rowss * scale * scale);
}

// ---------------------------------------------------------------------------
// K4: global L2 normalization in place
// ---------------------------------------------------------------------------
__global__ __launch_bounds__(256) void k4_scale(
    float* __restrict__ out, const float* __restrict__ gsum)
{
  const int n = blockIdx.y;
  const float g = 1.f / fmaxf(sqrtf(gsum[n]), EPS);
  size_t base = (size_t)n * KDIM * CDIM + (size_t)blockIdx.x * 1024 + threadIdx.x * 4;
  float4* p = (float4*)(out + base);
  float4 vv = *p;
  vv.x *= g; vv.y *= g; vv.z *= g; vv.w *= g;
  *p = vv;
}

extern "C" void kernel_launch(void* const* d_in, const int* in_sizes, int n_in,
                              void* d_out, int out_size, void* d_ws, size_t ws_size,
                              hipStream_t stream) {
  const float* x    = (const float*)d_in[0];   // [32,512,60,60]
  const float* w    = (const float*)d_in[1];   // [64,512]
  const float* cent = (const float*)d_in[2];   // [64,512]
  float* out = (float*)d_out;                  // [32, 64*512]
  float* ws = (float*)d_ws;

  float* a    = ws;                                   // 32*64*3600 = 7,372,800 f
  float* invn = a + (size_t)NN * KDIM * SDIM;         // 32*3600    =   115,200 f
  float* aggp = invn + (size_t)NN * SDIM;             // 4*32*64*512= 4,194,304 f
  float* gsum = aggp + (size_t)4 * NN * KDIM * CDIM;  // 32 f
  float* wT   = gsum + 64;                            // 512*64     =    32,768 f

  hipMemsetAsync(gsum, 0, NN * sizeof(float), stream);

  k0_transpose<<<dim3(128), 256, 0, stream>>>(w, wT);
  k1_softmax  <<<dim3(15, 32), 128, 0, stream>>>(x, wT, a, invn);
  k2_agg      <<<dim3(4, 32, 4), 256, 0, stream>>>(a, x, invn, aggp);
  k3_finalize <<<dim3(64, 32), 256, 0, stream>>>(a, aggp, cent, out, gsum);
  k4_scale    <<<dim3(32, 32), 256, 0, stream>>>(out, gsum);
}

// Round 7
// 806.729 us; speedup vs baseline: 1.0394x; 1.0394x over previous
//
#include <hip/hip_runtime.h>
#include <math.h>

#define EPS 1e-12f
#define NN 32
#define CDIM 512
#define SDIM 3600
#define KDIM 64

// ---------------------------------------------------------------------------
// K0: transpose W[64][512] -> wT[512][64]
// ---------------------------------------------------------------------------
__global__ __launch_bounds__(256) void k0_transpose(
    const float* __restrict__ w, float* __restrict__ wT)
{
  int i = blockIdx.x * 256 + threadIdx.x;   // 32768 total
  int k = i >> 9;        // /512
  int c = i & 511;
  wT[c * KDIM + k] = w[i];
}

// ---------------------------------------------------------------------------
// K1 v2: LDS-staged per-pixel GEMM + softmax.
// Block = 256 threads, 256 pixels (1 px/thread), loops C in chunks of 32.
// xs[32][256] staged cooperatively (coalesced float4), wt[32][64] broadcast.
// ---------------------------------------------------------------------------
__global__ __launch_bounds__(256) void k1_softmax(
    const float* __restrict__ x, const float* __restrict__ wT,
    float* __restrict__ a, float* __restrict__ invn_out)
{
  __shared__ float xs[32 * 256];   // 32 KB: xs[cc][px]
  __shared__ float wt[32 * 64];    //  8 KB: wt[cc][k]
  const int n = blockIdx.y;
  const int sbase = blockIdx.x * 256;
  const int tid = threadIdx.x;
  const int s_raw = sbase + tid;
  const bool valid = s_raw < SDIM;
  const float* xb = x + (size_t)n * CDIM * SDIM;
  const bool full = (sbase + 256) <= SDIM;   // uniform across block

  float acc[64];
  #pragma unroll
  for (int k = 0; k < 64; ++k) acc[k] = 0.f;
  float nrm = 0.f;

  for (int c0 = 0; c0 < CDIM; c0 += 32) {
    __syncthreads();
    // stage wt: 2048 floats = 512 float4, contiguous from wT + c0*64
    {
      const float4* src = (const float4*)(wT + c0 * 64);
      float4* dst = (float4*)wt;
      dst[tid]       = src[tid];
      dst[tid + 256] = src[tid + 256];
    }
    // stage xs: 32 rows x 256 px = 2048 float4-groups of 64 per row
    if (full) {
      #pragma unroll
      for (int it = 0; it < 8; ++it) {
        int idx = tid + it * 256;          // 0..2047
        int cc  = idx >> 6;                // 0..31
        int f4  = idx & 63;                // 0..63
        float4 v = *(const float4*)(xb + (size_t)(c0 + cc) * SDIM + sbase + f4 * 4);
        *(float4*)(&xs[cc * 256 + f4 * 4]) = v;
      }
    } else {
      #pragma unroll
      for (int it = 0; it < 8; ++it) {
        int idx = tid + it * 256;
        int cc  = idx >> 6;
        int f4  = idx & 63;
        #pragma unroll
        for (int j = 0; j < 4; ++j) {
          int s = sbase + f4 * 4 + j;
          xs[cc * 256 + f4 * 4 + j] =
              (s < SDIM) ? xb[(size_t)(c0 + cc) * SDIM + s] : 0.f;
        }
      }
    }
    __syncthreads();

    #pragma unroll 2
    for (int cc = 0; cc < 32; ++cc) {
      float xv = xs[cc * 256 + tid];
      nrm = fmaf(xv, xv, nrm);
      const float4* wr = (const float4*)(&wt[cc * 64]);
      #pragma unroll
      for (int q = 0; q < 16; ++q) {
        float4 w4 = wr[q];
        acc[q * 4 + 0] = fmaf(w4.x, xv, acc[q * 4 + 0]);
        acc[q * 4 + 1] = fmaf(w4.y, xv, acc[q * 4 + 1]);
        acc[q * 4 + 2] = fmaf(w4.z, xv, acc[q * 4 + 2]);
        acc[q * 4 + 3] = fmaf(w4.w, xv, acc[q * 4 + 3]);
      }
    }
  }

  // softmax over k of acc*invn
  float invn = 1.f / fmaxf(sqrtf(nrm), EPS);
  float m = acc[0];
  #pragma unroll
  for (int k = 1; k < 64; ++k) m = fmaxf(m, acc[k]);
  float sum = 0.f;
  #pragma unroll
  for (int k = 0; k < 64; ++k) {
    float e = __expf((acc[k] - m) * invn);
    acc[k] = e;
    sum += e;
  }
  float rs = 1.f / sum;

  if (valid) {
    float* ap = a + (size_t)n * KDIM * SDIM + s_raw;
    #pragma unroll
    for (int k = 0; k < 64; ++k) ap[(size_t)k * SDIM] = acc[k] * rs;
    invn_out[n * SDIM + s_raw] = invn;
  }
}

// ---------------------------------------------------------------------------
// K2 v2: aggp[sp][n][k][c] = sum_{s in split} a[n,k,s] * x[n,c,s]*invn[n,s]
// block: 64k x 64c tile, 256 threads (each 4k x 4c), s-chunked staging.
// Grid 8x32x4 = 1024 blocks (4 waves/SIMD target), LDS 34 KB (4 blocks/CU).
// ---------------------------------------------------------------------------
__global__ __launch_bounds__(256) void k2_agg(
    const float* __restrict__ a, const float* __restrict__ x,
    const float* __restrict__ invn, float* __restrict__ aggp)
{
  __shared__ float xs[60 * 68];    // xs[s][c], stride 68
  __shared__ float at[60 * 72];    // at[s][k], stride 72
  const int n = blockIdx.y;
  const int c0 = blockIdx.x * 64;
  const int sbase = blockIdx.z * 900;
  const int tk = threadIdx.x >> 4;   // 0..15 -> k = tk*4..tk*4+3
  const int tc = threadIdx.x & 15;   // 0..15 -> c = c0+tc*4..

  float acc[16];
  #pragma unroll
  for (int i = 0; i < 16; ++i) acc[i] = 0.f;

  for (int ch = 0; ch < 15; ++ch) {
    const int ss = sbase + ch * 60;
    __syncthreads();
    for (int i = threadIdx.x; i < 3840; i += 256) {     // 64c x 60s
      int c = i / 60;
      int s = i - c * 60;
      xs[s * 68 + c] = x[((size_t)n * CDIM + c0 + c) * SDIM + ss + s] *
                       invn[n * SDIM + ss + s];
    }
    for (int i = threadIdx.x; i < 3840; i += 256) {     // 64k x 60s
      int k = i / 60;
      int s = i - k * 60;
      at[s * 72 + k] = a[((size_t)n * KDIM + k) * SDIM + ss + s];
    }
    __syncthreads();
    #pragma unroll 4
    for (int s = 0; s < 60; ++s) {
      float4 av = *(const float4*)(&at[s * 72 + tk * 4]);
      float4 xv = *(const float4*)(&xs[s * 68 + tc * 4]);
      acc[ 0] = fmaf(av.x, xv.x, acc[ 0]);
      acc[ 1] = fmaf(av.x, xv.y, acc[ 1]);
      acc[ 2] = fmaf(av.x, xv.z, acc[ 2]);
      acc[ 3] = fmaf(av.x, xv.w, acc[ 3]);
      acc[ 4] = fmaf(av.y, xv.x, acc[ 4]);
      acc[ 5] = fmaf(av.y, xv.y, acc[ 5]);
      acc[ 6] = fmaf(av.y, xv.z, acc[ 6]);
      acc[ 7] = fmaf(av.y, xv.w, acc[ 7]);
      acc[ 8] = fmaf(av.z, xv.x, acc[ 8]);
      acc[ 9] = fmaf(av.z, xv.y, acc[ 9]);
      acc[10] = fmaf(av.z, xv.z, acc[10]);
      acc[11] = fmaf(av.z, xv.w, acc[11]);
      acc[12] = fmaf(av.w, xv.x, acc[12]);
      acc[13] = fmaf(av.w, xv.y, acc[13]);
      acc[14] = fmaf(av.w, xv.z, acc[14]);
      acc[15] = fmaf(av.w, xv.w, acc[15]);
    }
  }

  float* outp = aggp + ((size_t)blockIdx.z * NN + n) * KDIM * CDIM;
  #pragma unroll
  for (int j = 0; j < 4; ++j) {
    int k = tk * 4 + j;
    *(float4*)(&outp[(size_t)k * CDIM + c0 + tc * 4]) =
        make_float4(acc[j*4+0], acc[j*4+1], acc[j*4+2], acc[j*4+3]);
  }
}

// ---------------------------------------------------------------------------
// K3: per (n,k): asum = sum_s a ; row = sum_sp aggp - asum*centroid ;
//     intra-normalize ; write out ; atomicAdd per-n sumsq
// ---------------------------------------------------------------------------
__global__ __launch_bounds__(256) void k3_finalize(
    const float* __restrict__ a, const float* __restrict__ aggp,
    const float* __restrict__ cent, float* __restrict__ out,
    float* __restrict__ gsum)
{
  const int k = blockIdx.x;
  const int n = blockIdx.y;
  __shared__ float red[16];

  float p = 0.f;
  const float* ap = a + ((size_t)n * KDIM + k) * SDIM;
  for (int s = threadIdx.x; s < SDIM; s += 256) p += ap[s];
  #pragma unroll
  for (int o = 32; o > 0; o >>= 1) p += __shfl_xor(p, o);
  int wid = threadIdx.x >> 6;
  if ((threadIdx.x & 63) == 0) red[wid] = p;
  __syncthreads();
  float asum = red[0] + red[1] + red[2] + red[3];

  float v[2];
  float ss_ = 0.f;
  #pragma unroll
  for (int r = 0; r < 2; ++r) {
    int c = r * 256 + threadIdx.x;
    float t = 0.f;
    #pragma unroll
    for (int sp = 0; sp < 4; ++sp)
      t += aggp[(((size_t)sp * NN + n) * KDIM + k) * CDIM + c];
    t -= asum * cent[k * CDIM + c];
    v[r] = t;
    ss_ = fmaf(t, t, ss_);
  }
  #pragma unroll
  for (int o = 32; o > 0; o >>= 1) ss_ += __shfl_xor(ss_, o);
  if ((threadIdx.x & 63) == 0) red[8 + wid] = ss_;
  __syncthreads();
  float rowss = red[8] + red[9] + red[10] + red[11];

  float scale = 1.f / fmaxf(sqrtf(rowss), EPS);
  #pragma unroll
  for (int r = 0; r < 2; ++r)
    out[((size_t)n * KDIM + k) * CDIM + r * 256 + threadIdx.x] = v[r] * scale;
  if (threadIdx.x == 0) atomicAdd(&gsum[n], rowss * scale * scale);
}

// ---------------------------------------------------------------------------
// K4: global L2 normalization in place
// ---------------------------------------------------------------------------
__global__ __launch_bounds__(256) void k4_scale(
    float* __restrict__ out, const float* __restrict__ gsum)
{
  const int n = blockIdx.y;
  const float g = 1.f / fmaxf(sqrtf(gsum[n]), EPS);
  size_t base = (size_t)n * KDIM * CDIM + (size_t)blockIdx.x * 1024 + threadIdx.x * 4;
  float4* p = (float4*)(out + base);
  float4 vv = *p;
  vv.x *= g; vv.y *= g; vv.z *= g; vv.w *= g;
  *p = vv;
}

extern "C" void kernel_launch(void* const* d_in, const int* in_sizes, int n_in,
                              void* d_out, int out_size, void* d_ws, size_t ws_size,
                              hipStream_t stream) {
  const float* x    = (const float*)d_in[0];   // [32,512,60,60]
  const float* w    = (const float*)d_in[1];   // [64,512]
  const float* cent = (const float*)d_in[2];   // [64,512]
  float* out = (float*)d_out;                  // [32, 64*512]
  float* ws = (float*)d_ws;

  float* a    = ws;                                   // 32*64*3600 = 7,372,800 f
  float* invn = a + (size_t)NN * KDIM * SDIM;         // 32*3600    =   115,200 f
  float* aggp = invn + (size_t)NN * SDIM;             // 4*32*64*512= 4,194,304 f
  float* gsum = aggp + (size_t)4 * NN * KDIM * CDIM;  // 32 f
  float* wT   = gsum + 64;                            // 512*64     =    32,768 f

  hipMemsetAsync(gsum, 0, NN * sizeof(float), stream);

  k0_transpose<<<dim3(128), 256, 0, stream>>>(w, wT);
  k1_softmax  <<<dim3(15, 32), 256, 0, stream>>>(x, wT, a, invn);
  k2_agg      <<<dim3(8, 32, 4), 256, 0, stream>>>(a, x, invn, aggp);
  k3_finalize <<<dim3(64, 32), 256, 0, stream>>>(a, aggp, cent, out, gsum);
  k4_scale    <<<dim3(32, 32), 256, 0, stream>>>(out, gsum);
}